// Round 7
// baseline (125.165 us; speedup 1.0000x reference)
//
#include <hip/hip_runtime.h>
#include <math.h>

#define N 8192
#define D_IN 3
#define D_K 128
#define HID 256
#define N_RES 2
#define N_TRI 2730
#define N_EDGE 2048
#define EPS 1.1920929e-07f

typedef unsigned short u16;
typedef unsigned int u32;
typedef float f32x4 __attribute__((ext_vector_type(4)));
typedef short s16x8 __attribute__((ext_vector_type(8)));

// ---------------- workspace layout ----------------
#define OFF_LOGITS   0                        // N fp32 = 32,768 B
#define OFF_TRIOFF   32768                    // 11,008 B
#define OFF_TRICNT   43776                    // 11,008 B
#define OFF_MEMT     54784                    // 32,768 B
#define OFF_EOFF     87552                    // 8,192 B
#define OFF_ECNT     95744                    // 8,192 B
#define OFF_MEME     103936                   // 32,768 B
#define OFF_WPK      136704                   // 163,840 bf16 = 327,680 B
#define OFF_ROWINFO  464384                   // N int2 = 65,536 B

__device__ __forceinline__ u16 f2bf(float f) {   // RTNE fp32 -> bf16
    u32 u = __float_as_uint(f);
    u32 r = (u + 0x7fffu + ((u >> 16) & 1u)) >> 16;
    return (u16)r;
}
__device__ __forceinline__ u32 pack2bf(float a, float b) {
    return (u32)f2bf(a) | ((u32)f2bf(b) << 16);
}

// ---- setup: block 0 = bucket rows by tri & edge; blocks 1..20 = pack weights ----
__global__ __launch_bounds__(1024) void k_setup(
        const int* __restrict__ tri, const int* __restrict__ eids,
        const float* __restrict__ W0, const float* __restrict__ Wres,
        int* __restrict__ tri_off, int* __restrict__ tri_cnt, int* __restrict__ mem_t,
        int* __restrict__ e_off, int* __restrict__ e_cnt, int* __restrict__ mem_e,
        u16* __restrict__ Wpk, int2* __restrict__ row_info) {
    if (blockIdx.x != 0) {
        // ---- weight pack: 320 tiles x 64 lanes ----
        int tg = (blockIdx.x - 1) * 1024 + threadIdx.x;   // 0..20479
        int tile = tg >> 6, lane = tg & 63;
        int q = lane >> 4, c = lane & 15;
        u16 tmp[8];
        int dst;
        if (tile < 64) {                 // layer0: tile = nt*4 + kt
            int nt = tile >> 2, kt = tile & 3;
            int k0 = kt * 32 + q * 8, n = nt * 16 + c;
            dst = (tile * 64 + lane) * 8;
            #pragma unroll
            for (int j = 0; j < 8; ++j) tmp[j] = f2bf(W0[(k0 + j) * HID + n]);
        } else {                         // res layers: tl = nt*8 + kt
            int t2 = tile - 64;
            int r = t2 >> 7, tl = t2 & 127;
            int nt = tl >> 3, kt = tl & 7;
            int k0 = kt * 32 + q * 8, n = nt * 16 + c;
            dst = 32768 + r * 65536 + (tl * 64 + lane) * 8;
            const float* W = Wres + r * 65536;
            #pragma unroll
            for (int j = 0; j < 8; ++j) tmp[j] = f2bf(W[(k0 + j) * HID + n]);
        }
        *(s16x8*)&Wpk[dst] = *(s16x8*)tmp;
        return;
    }
    // ---- prep (one block, 1024 threads, shfl-hierarchical scans) ----
    __shared__ int sc[4096];
    __shared__ int ec[2048];
    __shared__ int wp[16];
    const int t = threadIdx.x, lane = t & 63, wid = t >> 6;
    for (int i = t; i < 4096; i += 1024) sc[i] = 0;
    for (int i = t; i < 2048; i += 1024) ec[i] = 0;
    __syncthreads();
    for (int n = t; n < N; n += 1024) {
        atomicAdd(&sc[tri[n]], 1);
        atomicAdd(&ec[eids[n]], 1);
    }
    __syncthreads();
    // tri scan: 4 elements/thread
    int a0 = sc[t*4], a1 = sc[t*4+1], a2 = sc[t*4+2], a3 = sc[t*4+3];
    int c0 = a0, c1 = c0 + a1, c2 = c1 + a2, c3 = c2 + a3;
    int ts = c3;
    #pragma unroll
    for (int o = 1; o < 64; o <<= 1) { int u = __shfl_up(ts, o); if (lane >= o) ts += u; }
    if (lane == 63) wp[wid] = ts;
    __syncthreads();
    if (wid == 0) {
        int v = (lane < 16) ? wp[lane] : 0;
        #pragma unroll
        for (int o = 1; o < 16; o <<= 1) { int u = __shfl_up(v, o); if (lane >= o) v += u; }
        if (lane < 16) wp[lane] = v;
    }
    __syncthreads();
    {
        int wexcl = wid ? wp[wid - 1] : 0;
        int texcl = wexcl + ts - c3;
        int o0 = texcl, o1 = texcl + c0, o2 = texcl + c1, o3 = texcl + c2;
        if (t*4+0 < N_TRI) { tri_off[t*4+0] = o0; tri_cnt[t*4+0] = a0; }
        if (t*4+1 < N_TRI) { tri_off[t*4+1] = o1; tri_cnt[t*4+1] = a1; }
        if (t*4+2 < N_TRI) { tri_off[t*4+2] = o2; tri_cnt[t*4+2] = a2; }
        if (t*4+3 < N_TRI) { tri_off[t*4+3] = o3; tri_cnt[t*4+3] = a3; }
        sc[t*4+0] = o0; sc[t*4+1] = o1; sc[t*4+2] = o2; sc[t*4+3] = o3;   // cursors
    }
    __syncthreads();   // wp reuse + cursor visibility
    // edge scan: 2 elements/thread
    int ea0 = ec[t*2], ea1 = ec[t*2+1];
    int f0 = ea0, f1 = f0 + ea1;
    int es = f1;
    #pragma unroll
    for (int o = 1; o < 64; o <<= 1) { int u = __shfl_up(es, o); if (lane >= o) es += u; }
    if (lane == 63) wp[wid] = es;
    __syncthreads();
    if (wid == 0) {
        int v = (lane < 16) ? wp[lane] : 0;
        #pragma unroll
        for (int o = 1; o < 16; o <<= 1) { int u = __shfl_up(v, o); if (lane >= o) v += u; }
        if (lane < 16) wp[lane] = v;
    }
    __syncthreads();
    {
        int wexcl = wid ? wp[wid - 1] : 0;
        int texcl = wexcl + es - f1;
        int eo0 = texcl, eo1 = texcl + f0;
        e_off[t*2+0] = eo0; e_cnt[t*2+0] = ea0;
        e_off[t*2+1] = eo1; e_cnt[t*2+1] = ea1;
        ec[t*2+0] = eo0; ec[t*2+1] = eo1;   // cursors
    }
    __syncthreads();
    for (int n = t; n < N; n += 1024) {
        int tt = tri[n];
        int p = atomicAdd(&sc[tt], 1);
        mem_t[p] = n;
        int q2 = atomicAdd(&ec[eids[n]], 1);
        mem_e[q2] = n;
        // per-row bucket info (tri_off/tri_cnt written by this block pre-barrier)
        row_info[n] = make_int2(tri_off[tt], tri_cnt[tt]);
    }
}

// ---- fused attention + MFMA MLP: 16 rows/block, 512 threads (8 waves) ----
// wave w owns cols w*32 + {0..15, 16..31}; attn phase: wave w computes rows 2w, 2w+1.
__global__ __launch_bounds__(512) void k_fused(
        const float* __restrict__ ef,
        const float* __restrict__ Wq, const float* __restrict__ bq,
        const float* __restrict__ Wk, const float* __restrict__ bk,
        const float* __restrict__ Wv, const float* __restrict__ bv,
        const int2* __restrict__ row_info, const int* __restrict__ mem_t,
        const float* __restrict__ b0, const float* __restrict__ rms_w,
        const float* __restrict__ bres, const float* __restrict__ Wout,
        const float* __restrict__ bout, const u16* __restrict__ Wpk,
        float* __restrict__ logits) {
    __shared__ u16 X[16][264];
    __shared__ float red[8][16];
    const int tid = threadIdx.x;
    const int w = tid >> 6, lane = tid & 63;
    const int q = lane >> 4, c = lane & 15;
    const int base = blockIdx.x * 16;
    const int colb = w * 32 + c;

    // ================= attention phase =================
    {
        const int d0 = lane * 2, d1 = d0 + 1;
        float wq0a = Wq[d0], wq1a = Wq[D_K + d0], wq2a = Wq[2*D_K + d0], bqa = bq[d0];
        float wq0b = Wq[d1], wq1b = Wq[D_K + d1], wq2b = Wq[2*D_K + d1], bqb = bq[d1];
        float wk0a = Wk[d0], wk1a = Wk[D_K + d0], wk2a = Wk[2*D_K + d0], bka = bk[d0];
        float wk0b = Wk[d1], wk1b = Wk[D_K + d1], wk2b = Wk[2*D_K + d1], bkb = bk[d1];
        float wv0a = Wv[d0], wv1a = Wv[D_K + d0], wv2a = Wv[2*D_K + d0], bva = bv[d0];
        float wv0b = Wv[d1], wv1b = Wv[D_K + d1], wv2b = Wv[2*D_K + d1], bvb = bv[d1];
        const float scale = 0.08838834764831845f;  // 1/sqrt(128)

        #pragma unroll
        for (int rr = 0; rr < 2; ++rr) {
            int lrow = 2 * w + rr;
            int row = base + lrow;
            float e0 = ef[row*3+0], e1 = ef[row*3+1], e2 = ef[row*3+2];
            float qa = bqa + e0*wq0a + e1*wq1a + e2*wq2a;
            float qb = bqb + e0*wq0b + e1*wq1b + e2*wq2b;
            int2 ri = row_info[row];
            int off = ri.x, cnt = ri.y;
            float m = -INFINITY, l = 0.f, acca = 0.f, accb = 0.f;
            for (int bs = 0; bs < cnt; bs += 64) {
                int nn = cnt - bs; if (nn > 64) nn = 64;
                float g0 = 0.f, g1 = 0.f, g2 = 0.f;
                if (lane < nn) {
                    int j = mem_t[off + bs + lane];
                    g0 = ef[j*3+0]; g1 = ef[j*3+1]; g2 = ef[j*3+2];
                }
                for (int ii = 0; ii < nn; ++ii) {
                    float h0 = __shfl(g0, ii), h1 = __shfl(g1, ii), h2 = __shfl(g2, ii);
                    float ka = bka + h0*wk0a + h1*wk1a + h2*wk2a;
                    float kb = bkb + h0*wk0b + h1*wk1b + h2*wk2b;
                    float p = qa * ka + qb * kb;
                    #pragma unroll
                    for (int o = 32; o > 0; o >>= 1) p += __shfl_xor(p, o);
                    float s = p * scale;
                    float va = bva + h0*wv0a + h1*wv1a + h2*wv2a;
                    float vb = bvb + h0*wv0b + h1*wv1b + h2*wv2b;
                    float mn = fmaxf(m, s);
                    float rs = expf(m - mn);    // first iter: exp(-inf)=0
                    float ws = expf(s - mn);
                    l    = l * rs + ws;
                    acca = acca * rs + ws * va;
                    accb = accb * rs + ws * vb;
                    m = mn;
                }
            }
            float inv = 1.f / l;
            *(u32*)&X[lrow][d0] = pack2bf(acca * inv, accb * inv);
        }
    }
    __syncthreads();

    // ================= MFMA MLP phase =================
    const s16x8* Bp = (const s16x8*)Wpk;
    float h[2][4];
    f32x4 acc[2];
    const f32x4 zero = {0.f, 0.f, 0.f, 0.f};

    // layer0: [16x128] @ [128x256]
    #pragma unroll
    for (int nt = 0; nt < 2; ++nt) acc[nt] = zero;
    #pragma unroll
    for (int kt = 0; kt < 4; ++kt) {
        s16x8 a = *(const s16x8*)&X[c][kt * 32 + q * 8];
        #pragma unroll
        for (int nt = 0; nt < 2; ++nt) {
            s16x8 b = Bp[((w * 2 + nt) * 4 + kt) * 64 + lane];
            acc[nt] = __builtin_amdgcn_mfma_f32_16x16x32_bf16(a, b, acc[nt], 0, 0, 0);
        }
    }
    #pragma unroll
    for (int nt = 0; nt < 2; ++nt) {
        float bb = b0[colb + nt * 16];
        #pragma unroll
        for (int rg = 0; rg < 4; ++rg) h[nt][rg] = acc[nt][rg] + bb;
    }

    // res blocks
    for (int ir = 0; ir < N_RES; ++ir) {
        float part[4];
        #pragma unroll
        for (int rg = 0; rg < 4; ++rg) {
            part[rg] = h[0][rg] * h[0][rg] + h[1][rg] * h[1][rg];
            #pragma unroll
            for (int o = 1; o < 16; o <<= 1) part[rg] += __shfl_xor(part[rg], o);
        }
        if (c == 0) {
            #pragma unroll
            for (int rg = 0; rg < 4; ++rg) red[w][q * 4 + rg] = part[rg];
        }
        __syncthreads();   // red visible; all waves past previous X reads
        float sc4[4];
        #pragma unroll
        for (int rg = 0; rg < 4; ++rg) {
            int rr = q * 4 + rg;
            float ms = (red[0][rr] + red[1][rr] + red[2][rr] + red[3][rr]
                      + red[4][rr] + red[5][rr] + red[6][rr] + red[7][rr]) * (1.f / HID);
            sc4[rg] = rsqrtf(ms + EPS);
        }
        #pragma unroll
        for (int nt = 0; nt < 2; ++nt) {
            float gg = rms_w[ir * HID + colb + nt * 16];
            #pragma unroll
            for (int rg = 0; rg < 4; ++rg)
                X[q * 4 + rg][colb + nt * 16] = f2bf(h[nt][rg] * sc4[rg] * gg);
        }
        __syncthreads();   // hn visible

        const s16x8* Br = Bp + 4096 + ir * 8192;
        #pragma unroll
        for (int nt = 0; nt < 2; ++nt) acc[nt] = zero;
        #pragma unroll
        for (int kt = 0; kt < 8; ++kt) {
            s16x8 a = *(const s16x8*)&X[c][kt * 32 + q * 8];
            #pragma unroll
            for (int nt = 0; nt < 2; ++nt) {
                s16x8 b = Br[((w * 2 + nt) * 8 + kt) * 64 + lane];
                acc[nt] = __builtin_amdgcn_mfma_f32_16x16x32_bf16(a, b, acc[nt], 0, 0, 0);
            }
        }
        #pragma unroll
        for (int nt = 0; nt < 2; ++nt) {
            float bb = bres[ir * HID + colb + nt * 16];
            #pragma unroll
            for (int rg = 0; rg < 4; ++rg) h[nt][rg] += fmaxf(acc[nt][rg] + bb, 0.f);
        }
    }

    // logits
    {
        float wo0 = Wout[colb], wo1 = Wout[colb + 16];
        float part[4];
        #pragma unroll
        for (int rg = 0; rg < 4; ++rg) {
            part[rg] = h[0][rg] * wo0 + h[1][rg] * wo1;
            #pragma unroll
            for (int o = 1; o < 16; o <<= 1) part[rg] += __shfl_xor(part[rg], o);
        }
        if (c == 0) {
            #pragma unroll
            for (int rg = 0; rg < 4; ++rg) red[w][q * 4 + rg] = part[rg];
        }
        __syncthreads();
        if (tid < 16) {
            float s = bout[0];
            #pragma unroll
            for (int w2 = 0; w2 < 8; ++w2) s += red[w2][tid];
            logits[base + tid] = s;
        }
    }
}

// ---- scatter-softmax over edge buckets: one wave per edge ----
__global__ __launch_bounds__(256) void k_segsoft(
        const float* __restrict__ logits, const int* __restrict__ e_off,
        const int* __restrict__ e_cnt, const int* __restrict__ mem_e,
        float* __restrict__ out) {
    int e = (blockIdx.x * 256 + threadIdx.x) >> 6;
    int lane = threadIdx.x & 63;
    int off = e_off[e], cnt = e_cnt[e];
    float mx = -INFINITY;
    for (int i = lane; i < cnt; i += 64) mx = fmaxf(mx, logits[mem_e[off + i]]);
    #pragma unroll
    for (int o = 32; o > 0; o >>= 1) mx = fmaxf(mx, __shfl_xor(mx, o));
    float s = 0.f;
    for (int i = lane; i < cnt; i += 64) s += expf(logits[mem_e[off + i]] - mx);
    #pragma unroll
    for (int o = 32; o > 0; o >>= 1) s += __shfl_xor(s, o);
    float inv = 1.f / s;
    for (int i = lane; i < cnt; i += 64) {
        int m = mem_e[off + i];
        out[m] = expf(logits[m] - mx) * inv;
    }
}

extern "C" void kernel_launch(void* const* d_in, const int* in_sizes, int n_in,
                              void* d_out, int out_size, void* d_ws, size_t ws_size,
                              hipStream_t stream) {
    const float* ef   = (const float*)d_in[0];
    const int*   eids = (const int*)d_in[1];
    const int*   tri  = (const int*)d_in[2];
    const float* Wq = (const float*)d_in[3];
    const float* bq = (const float*)d_in[4];
    const float* Wk = (const float*)d_in[5];
    const float* bk = (const float*)d_in[6];
    const float* Wv = (const float*)d_in[7];
    const float* bv = (const float*)d_in[8];
    const float* W0 = (const float*)d_in[9];
    const float* b0 = (const float*)d_in[10];
    const float* rms_w = (const float*)d_in[11];
    const float* Wres  = (const float*)d_in[12];
    const float* bres  = (const float*)d_in[13];
    const float* Wout  = (const float*)d_in[14];
    const float* bout  = (const float*)d_in[15];
    float* out = (float*)d_out;

    char* ws = (char*)d_ws;
    float* logits   = (float*)(ws + OFF_LOGITS);
    int*   tri_off  = (int*)(ws + OFF_TRIOFF);
    int*   tri_cnt  = (int*)(ws + OFF_TRICNT);
    int*   mem_t    = (int*)(ws + OFF_MEMT);
    int*   e_off    = (int*)(ws + OFF_EOFF);
    int*   e_cnt    = (int*)(ws + OFF_ECNT);
    int*   mem_e    = (int*)(ws + OFF_MEME);
    u16*   Wpk      = (u16*)(ws + OFF_WPK);
    int2*  row_info = (int2*)(ws + OFF_ROWINFO);

    hipLaunchKernelGGL(k_setup, dim3(21), dim3(1024), 0, stream,
                       tri, eids, W0, Wres,
                       tri_off, tri_cnt, mem_t, e_off, e_cnt, mem_e, Wpk, row_info);
    hipLaunchKernelGGL(k_fused, dim3(N / 16), dim3(512), 0, stream,
                       ef, Wq, bq, Wk, bk, Wv, bv,
                       row_info, mem_t,
                       b0, rms_w, bres, Wout, bout, Wpk, logits);
    hipLaunchKernelGGL(k_segsoft, dim3(N_EDGE / 4), dim3(256), 0, stream,
                       logits, e_off, e_cnt, mem_e, out);
}

// Round 8
// 117.529 us; speedup vs baseline: 1.0650x; 1.0650x over previous
//
#include <hip/hip_runtime.h>
#include <math.h>

#define N 8192
#define D_IN 3
#define D_K 128
#define HID 256
#define N_RES 2
#define N_TRI 2730
#define N_EDGE 2048
#define EPS 1.1920929e-07f

typedef unsigned short u16;
typedef unsigned int u32;
typedef float f32x4 __attribute__((ext_vector_type(4)));
typedef short s16x8 __attribute__((ext_vector_type(8)));

// ---------------- workspace layout ----------------
#define OFF_LOGITS   0                        // N fp32 = 32,768 B
#define OFF_TRIOFF   32768                    // 11,008 B
#define OFF_TRICNT   43776                    // 11,008 B
#define OFF_MEMT     54784                    // 32,768 B
#define OFF_EOFF     87552                    // 8,192 B
#define OFF_ECNT     95744                    // 8,192 B
#define OFF_MEME     103936                   // 32,768 B
#define OFF_WPK      136704                   // 163,840 bf16 = 327,680 B

__device__ __forceinline__ u16 f2bf(float f) {   // RTNE fp32 -> bf16
    u32 u = __float_as_uint(f);
    u32 r = (u + 0x7fffu + ((u >> 16) & 1u)) >> 16;
    return (u16)r;
}
__device__ __forceinline__ u32 pack2bf(float a, float b) {
    return (u32)f2bf(a) | ((u32)f2bf(b) << 16);
}

// ---- setup: block 0 = bucket rows by tri & edge; blocks 1..20 = pack weights ----
__global__ __launch_bounds__(1024) void k_setup(
        const int* __restrict__ tri, const int* __restrict__ eids,
        const float* __restrict__ W0, const float* __restrict__ Wres,
        int* __restrict__ tri_off, int* __restrict__ tri_cnt, int* __restrict__ mem_t,
        int* __restrict__ e_off, int* __restrict__ e_cnt, int* __restrict__ mem_e,
        u16* __restrict__ Wpk) {
    if (blockIdx.x != 0) {
        // ---- weight pack: 320 tiles x 64 lanes ----
        int tg = (blockIdx.x - 1) * 1024 + threadIdx.x;   // 0..20479
        int tile = tg >> 6, lane = tg & 63;
        int q = lane >> 4, c = lane & 15;
        u16 tmp[8];
        int dst;
        if (tile < 64) {                 // layer0: tile = nt*4 + kt
            int nt = tile >> 2, kt = tile & 3;
            int k0 = kt * 32 + q * 8, n = nt * 16 + c;
            dst = (tile * 64 + lane) * 8;
            #pragma unroll
            for (int j = 0; j < 8; ++j) tmp[j] = f2bf(W0[(k0 + j) * HID + n]);
        } else {                         // res layers: tl = nt*8 + kt
            int t2 = tile - 64;
            int r = t2 >> 7, tl = t2 & 127;
            int nt = tl >> 3, kt = tl & 7;
            int k0 = kt * 32 + q * 8, n = nt * 16 + c;
            dst = 32768 + r * 65536 + (tl * 64 + lane) * 8;
            const float* W = Wres + r * 65536;
            #pragma unroll
            for (int j = 0; j < 8; ++j) tmp[j] = f2bf(W[(k0 + j) * HID + n]);
        }
        *(s16x8*)&Wpk[dst] = *(s16x8*)tmp;
        return;
    }
    // ---- prep (one block, 1024 threads, shfl-hierarchical scans) ----
    __shared__ int sc[4096];
    __shared__ int ec[2048];
    __shared__ int wp[16];
    const int t = threadIdx.x, lane = t & 63, wid = t >> 6;
    for (int i = t; i < 4096; i += 1024) sc[i] = 0;
    for (int i = t; i < 2048; i += 1024) ec[i] = 0;
    __syncthreads();
    for (int n = t; n < N; n += 1024) {
        atomicAdd(&sc[tri[n]], 1);
        atomicAdd(&ec[eids[n]], 1);
    }
    __syncthreads();
    // tri scan: 4 elements/thread
    int a0 = sc[t*4], a1 = sc[t*4+1], a2 = sc[t*4+2], a3 = sc[t*4+3];
    int c0 = a0, c1 = c0 + a1, c2 = c1 + a2, c3 = c2 + a3;
    int ts = c3;
    #pragma unroll
    for (int o = 1; o < 64; o <<= 1) { int u = __shfl_up(ts, o); if (lane >= o) ts += u; }
    if (lane == 63) wp[wid] = ts;
    __syncthreads();
    if (wid == 0) {
        int v = (lane < 16) ? wp[lane] : 0;
        #pragma unroll
        for (int o = 1; o < 16; o <<= 1) { int u = __shfl_up(v, o); if (lane >= o) v += u; }
        if (lane < 16) wp[lane] = v;
    }
    __syncthreads();
    {
        int wexcl = wid ? wp[wid - 1] : 0;
        int texcl = wexcl + ts - c3;
        int o0 = texcl, o1 = texcl + c0, o2 = texcl + c1, o3 = texcl + c2;
        if (t*4+0 < N_TRI) { tri_off[t*4+0] = o0; tri_cnt[t*4+0] = a0; }
        if (t*4+1 < N_TRI) { tri_off[t*4+1] = o1; tri_cnt[t*4+1] = a1; }
        if (t*4+2 < N_TRI) { tri_off[t*4+2] = o2; tri_cnt[t*4+2] = a2; }
        if (t*4+3 < N_TRI) { tri_off[t*4+3] = o3; tri_cnt[t*4+3] = a3; }
        sc[t*4+0] = o0; sc[t*4+1] = o1; sc[t*4+2] = o2; sc[t*4+3] = o3;   // cursors
    }
    __syncthreads();   // wp reuse + cursor visibility
    // edge scan: 2 elements/thread
    int ea0 = ec[t*2], ea1 = ec[t*2+1];
    int f0 = ea0, f1 = f0 + ea1;
    int es = f1;
    #pragma unroll
    for (int o = 1; o < 64; o <<= 1) { int u = __shfl_up(es, o); if (lane >= o) es += u; }
    if (lane == 63) wp[wid] = es;
    __syncthreads();
    if (wid == 0) {
        int v = (lane < 16) ? wp[lane] : 0;
        #pragma unroll
        for (int o = 1; o < 16; o <<= 1) { int u = __shfl_up(v, o); if (lane >= o) v += u; }
        if (lane < 16) wp[lane] = v;
    }
    __syncthreads();
    {
        int wexcl = wid ? wp[wid - 1] : 0;
        int texcl = wexcl + es - f1;
        int eo0 = texcl, eo1 = texcl + f0;
        e_off[t*2+0] = eo0; e_cnt[t*2+0] = ea0;
        e_off[t*2+1] = eo1; e_cnt[t*2+1] = ea1;
        ec[t*2+0] = eo0; ec[t*2+1] = eo1;   // cursors
    }
    __syncthreads();
    for (int n = t; n < N; n += 1024) {
        int p = atomicAdd(&sc[tri[n]], 1);
        mem_t[p] = n;
        int q2 = atomicAdd(&ec[eids[n]], 1);
        mem_e[q2] = n;
    }
}

// ---- fused attention + MFMA MLP: 16 rows/block, 512 threads (8 waves) ----
// wave w owns cols w*32 + {0..15, 16..31}; attn phase: wave w computes rows 2w, 2w+1.
__global__ __launch_bounds__(512) void k_fused(
        const float* __restrict__ ef, const int* __restrict__ tri,
        const float* __restrict__ Wq, const float* __restrict__ bq,
        const float* __restrict__ Wk, const float* __restrict__ bk,
        const float* __restrict__ Wv, const float* __restrict__ bv,
        const int* __restrict__ tri_off, const int* __restrict__ tri_cnt,
        const int* __restrict__ mem_t,
        const float* __restrict__ b0, const float* __restrict__ rms_w,
        const float* __restrict__ bres, const float* __restrict__ Wout,
        const float* __restrict__ bout, const u16* __restrict__ Wpk,
        float* __restrict__ logits) {
    __shared__ u16 X[16][264];
    __shared__ float red[8][16];
    const int tid = threadIdx.x;
    const int w = tid >> 6, lane = tid & 63;
    const int q = lane >> 4, c = lane & 15;
    const int base = blockIdx.x * 16;
    const int colb = w * 32 + c;

    // ================= attention phase =================
    {
        const int d0 = lane * 2, d1 = d0 + 1;
        float wq0a = Wq[d0], wq1a = Wq[D_K + d0], wq2a = Wq[2*D_K + d0], bqa = bq[d0];
        float wq0b = Wq[d1], wq1b = Wq[D_K + d1], wq2b = Wq[2*D_K + d1], bqb = bq[d1];
        float wk0a = Wk[d0], wk1a = Wk[D_K + d0], wk2a = Wk[2*D_K + d0], bka = bk[d0];
        float wk0b = Wk[d1], wk1b = Wk[D_K + d1], wk2b = Wk[2*D_K + d1], bkb = bk[d1];
        float wv0a = Wv[d0], wv1a = Wv[D_K + d0], wv2a = Wv[2*D_K + d0], bva = bv[d0];
        float wv0b = Wv[d1], wv1b = Wv[D_K + d1], wv2b = Wv[2*D_K + d1], bvb = bv[d1];
        const float scale = 0.08838834764831845f;  // 1/sqrt(128)

        #pragma unroll
        for (int rr = 0; rr < 2; ++rr) {
            int lrow = 2 * w + rr;
            int row = base + lrow;
            float e0 = ef[row*3+0], e1 = ef[row*3+1], e2 = ef[row*3+2];
            float qa = bqa + e0*wq0a + e1*wq1a + e2*wq2a;
            float qb = bqb + e0*wq0b + e1*wq1b + e2*wq2b;
            int tt = tri[row];
            int off = tri_off[tt], cnt = tri_cnt[tt];
            float m = -INFINITY, l = 0.f, acca = 0.f, accb = 0.f;
            for (int bs = 0; bs < cnt; bs += 64) {
                int nn = cnt - bs; if (nn > 64) nn = 64;
                float g0 = 0.f, g1 = 0.f, g2 = 0.f;
                if (lane < nn) {
                    int j = mem_t[off + bs + lane];
                    g0 = ef[j*3+0]; g1 = ef[j*3+1]; g2 = ef[j*3+2];
                }
                for (int ii = 0; ii < nn; ++ii) {
                    float h0 = __shfl(g0, ii), h1 = __shfl(g1, ii), h2 = __shfl(g2, ii);
                    float ka = bka + h0*wk0a + h1*wk1a + h2*wk2a;
                    float kb = bkb + h0*wk0b + h1*wk1b + h2*wk2b;
                    float p = qa * ka + qb * kb;
                    #pragma unroll
                    for (int o = 32; o > 0; o >>= 1) p += __shfl_xor(p, o);
                    float s = p * scale;
                    float va = bva + h0*wv0a + h1*wv1a + h2*wv2a;
                    float vb = bvb + h0*wv0b + h1*wv1b + h2*wv2b;
                    float mn = fmaxf(m, s);
                    float rs = expf(m - mn);    // first iter: exp(-inf)=0
                    float ws = expf(s - mn);
                    l    = l * rs + ws;
                    acca = acca * rs + ws * va;
                    accb = accb * rs + ws * vb;
                    m = mn;
                }
            }
            float inv = 1.f / l;
            *(u32*)&X[lrow][d0] = pack2bf(acca * inv, accb * inv);
        }
    }
    __syncthreads();

    // ================= MFMA MLP phase =================
    const s16x8* Bp = (const s16x8*)Wpk;
    float h[2][4];
    f32x4 acc[2];
    const f32x4 zero = {0.f, 0.f, 0.f, 0.f};

    // layer0: [16x128] @ [128x256]
    #pragma unroll
    for (int nt = 0; nt < 2; ++nt) acc[nt] = zero;
    #pragma unroll
    for (int kt = 0; kt < 4; ++kt) {
        s16x8 a = *(const s16x8*)&X[c][kt * 32 + q * 8];
        #pragma unroll
        for (int nt = 0; nt < 2; ++nt) {
            s16x8 b = Bp[((w * 2 + nt) * 4 + kt) * 64 + lane];
            acc[nt] = __builtin_amdgcn_mfma_f32_16x16x32_bf16(a, b, acc[nt], 0, 0, 0);
        }
    }
    #pragma unroll
    for (int nt = 0; nt < 2; ++nt) {
        float bb = b0[colb + nt * 16];
        #pragma unroll
        for (int rg = 0; rg < 4; ++rg) h[nt][rg] = acc[nt][rg] + bb;
    }

    // res blocks
    for (int ir = 0; ir < N_RES; ++ir) {
        float part[4];
        #pragma unroll
        for (int rg = 0; rg < 4; ++rg) {
            part[rg] = h[0][rg] * h[0][rg] + h[1][rg] * h[1][rg];
            #pragma unroll
            for (int o = 1; o < 16; o <<= 1) part[rg] += __shfl_xor(part[rg], o);
        }
        if (c == 0) {
            #pragma unroll
            for (int rg = 0; rg < 4; ++rg) red[w][q * 4 + rg] = part[rg];
        }
        __syncthreads();   // red visible; all waves past previous X reads
        float sc4[4];
        #pragma unroll
        for (int rg = 0; rg < 4; ++rg) {
            int rr = q * 4 + rg;
            float ms = (red[0][rr] + red[1][rr] + red[2][rr] + red[3][rr]
                      + red[4][rr] + red[5][rr] + red[6][rr] + red[7][rr]) * (1.f / HID);
            sc4[rg] = rsqrtf(ms + EPS);
        }
        #pragma unroll
        for (int nt = 0; nt < 2; ++nt) {
            float gg = rms_w[ir * HID + colb + nt * 16];
            #pragma unroll
            for (int rg = 0; rg < 4; ++rg)
                X[q * 4 + rg][colb + nt * 16] = f2bf(h[nt][rg] * sc4[rg] * gg);
        }
        __syncthreads();   // hn visible

        const s16x8* Br = Bp + 4096 + ir * 8192;
        #pragma unroll
        for (int nt = 0; nt < 2; ++nt) acc[nt] = zero;
        #pragma unroll
        for (int kt = 0; kt < 8; ++kt) {
            s16x8 a = *(const s16x8*)&X[c][kt * 32 + q * 8];
            #pragma unroll
            for (int nt = 0; nt < 2; ++nt) {
                s16x8 b = Br[((w * 2 + nt) * 8 + kt) * 64 + lane];
                acc[nt] = __builtin_amdgcn_mfma_f32_16x16x32_bf16(a, b, acc[nt], 0, 0, 0);
            }
        }
        #pragma unroll
        for (int nt = 0; nt < 2; ++nt) {
            float bb = bres[ir * HID + colb + nt * 16];
            #pragma unroll
            for (int rg = 0; rg < 4; ++rg) h[nt][rg] += fmaxf(acc[nt][rg] + bb, 0.f);
        }
    }

    // logits
    {
        float wo0 = Wout[colb], wo1 = Wout[colb + 16];
        float part[4];
        #pragma unroll
        for (int rg = 0; rg < 4; ++rg) {
            part[rg] = h[0][rg] * wo0 + h[1][rg] * wo1;
            #pragma unroll
            for (int o = 1; o < 16; o <<= 1) part[rg] += __shfl_xor(part[rg], o);
        }
        if (c == 0) {
            #pragma unroll
            for (int rg = 0; rg < 4; ++rg) red[w][q * 4 + rg] = part[rg];
        }
        __syncthreads();
        if (tid < 16) {
            float s = bout[0];
            #pragma unroll
            for (int w2 = 0; w2 < 8; ++w2) s += red[w2][tid];
            logits[base + tid] = s;
        }
    }
}

// ---- scatter-softmax over edge buckets: one wave per edge ----
__global__ __launch_bounds__(256) void k_segsoft(
        const float* __restrict__ logits, const int* __restrict__ e_off,
        const int* __restrict__ e_cnt, const int* __restrict__ mem_e,
        float* __restrict__ out) {
    int e = (blockIdx.x * 256 + threadIdx.x) >> 6;
    int lane = threadIdx.x & 63;
    int off = e_off[e], cnt = e_cnt[e];
    float mx = -INFINITY;
    for (int i = lane; i < cnt; i += 64) mx = fmaxf(mx, logits[mem_e[off + i]]);
    #pragma unroll
    for (int o = 32; o > 0; o >>= 1) mx = fmaxf(mx, __shfl_xor(mx, o));
    float s = 0.f;
    for (int i = lane; i < cnt; i += 64) s += expf(logits[mem_e[off + i]] - mx);
    #pragma unroll
    for (int o = 32; o > 0; o >>= 1) s += __shfl_xor(s, o);
    float inv = 1.f / s;
    for (int i = lane; i < cnt; i += 64) {
        int m = mem_e[off + i];
        out[m] = expf(logits[m] - mx) * inv;
    }
}

extern "C" void kernel_launch(void* const* d_in, const int* in_sizes, int n_in,
                              void* d_out, int out_size, void* d_ws, size_t ws_size,
                              hipStream_t stream) {
    const float* ef   = (const float*)d_in[0];
    const int*   eids = (const int*)d_in[1];
    const int*   tri  = (const int*)d_in[2];
    const float* Wq = (const float*)d_in[3];
    const float* bq = (const float*)d_in[4];
    const float* Wk = (const float*)d_in[5];
    const float* bk = (const float*)d_in[6];
    const float* Wv = (const float*)d_in[7];
    const float* bv = (const float*)d_in[8];
    const float* W0 = (const float*)d_in[9];
    const float* b0 = (const float*)d_in[10];
    const float* rms_w = (const float*)d_in[11];
    const float* Wres  = (const float*)d_in[12];
    const float* bres  = (const float*)d_in[13];
    const float* Wout  = (const float*)d_in[14];
    const float* bout  = (const float*)d_in[15];
    float* out = (float*)d_out;

    char* ws = (char*)d_ws;
    float* logits  = (float*)(ws + OFF_LOGITS);
    int*   tri_off = (int*)(ws + OFF_TRIOFF);
    int*   tri_cnt = (int*)(ws + OFF_TRICNT);
    int*   mem_t   = (int*)(ws + OFF_MEMT);
    int*   e_off   = (int*)(ws + OFF_EOFF);
    int*   e_cnt   = (int*)(ws + OFF_ECNT);
    int*   mem_e   = (int*)(ws + OFF_MEME);
    u16*   Wpk     = (u16*)(ws + OFF_WPK);

    hipLaunchKernelGGL(k_setup, dim3(21), dim3(1024), 0, stream,
                       tri, eids, W0, Wres,
                       tri_off, tri_cnt, mem_t, e_off, e_cnt, mem_e, Wpk);
    hipLaunchKernelGGL(k_fused, dim3(N / 16), dim3(512), 0, stream,
                       ef, tri, Wq, bq, Wk, bk, Wv, bv,
                       tri_off, tri_cnt, mem_t,
                       b0, rms_w, bres, Wout, bout, Wpk, logits);
    hipLaunchKernelGGL(k_segsoft, dim3(N_EDGE / 4), dim3(256), 0, stream,
                       logits, e_off, e_cnt, mem_e, out);
}